// Round 1
// baseline (140.580 us; speedup 1.0000x reference)
//
#include <hip/hip_runtime.h>
#include <hip/hip_bf16.h>

// ContactPredictionHead: logits[b,i,j,o] = sum_d h[b,i,d]*h[b,j,d]*Wp[o,d] + bias[o]
// (diff term is antisymmetric and cancels under the (i,j)-symmetrization; prod is symmetric.)
// Cast as batched GEMM: per batch  C[2048 x 4096] = A[2048 x 1280] * Beff^T,
//   Beff[2j+o, d] = h[b,j,d] * Wp[o,d],  output row-major matches d_out exactly.

typedef __attribute__((ext_vector_type(8))) short bf16x8;
typedef __attribute__((ext_vector_type(4))) float f32x4;

constexpr int cB = 4, cL = 2048, cD = 1280, cO = 2;
constexpr int BM = 128, BN = 128, BK = 64;
constexpr int MT = cL / BM;           // 16
constexpr int NT = (cL * cO) / BN;    // 32
constexpr int KT = cD / BK;           // 20
constexpr int NBLK = cB * MT * NT;    // 2048  (divisible by 8 -> bijective XCD swizzle)
constexpr int NROW = cL * cO;         // 4096

__device__ __forceinline__ unsigned short f2bf(float f) {
  // round-to-nearest-even f32 -> bf16 (inputs are finite; no NaN handling needed)
  unsigned int u = __float_as_uint(f);
  u += 0x7fffu + ((u >> 16) & 1u);
  return (unsigned short)(u >> 16);
}

#define GLOAD_LDS16(g, l)                                           \
  __builtin_amdgcn_global_load_lds(                                 \
      (const __attribute__((address_space(1))) void*)(g),           \
      (__attribute__((address_space(3))) void*)(l), 16, 0, 0)

// ---------------- pack: h -> bf16 A, (h*Wp) -> bf16 Beff ----------------
constexpr int ACH = cB * cL * cD / 8;       // 1,310,720 chunks of 8
constexpr int BCH = cB * 2 * cL * cD / 8;   // 2,621,440 chunks of 8

__global__ __launch_bounds__(256) void cph_pack(
    const float* __restrict__ h, const float* __restrict__ W,
    unsigned short* __restrict__ Apk, unsigned short* __restrict__ Bpk) {
  int idx = blockIdx.x * 256 + threadIdx.x;
  if (idx < ACH) {
    const float* src = h + (size_t)idx * 8;
    float4 x0 = *(const float4*)src;
    float4 x1 = *(const float4*)(src + 4);
    bf16x8 v;
    v[0] = (short)f2bf(x0.x); v[1] = (short)f2bf(x0.y);
    v[2] = (short)f2bf(x0.z); v[3] = (short)f2bf(x0.w);
    v[4] = (short)f2bf(x1.x); v[5] = (short)f2bf(x1.y);
    v[6] = (short)f2bf(x1.z); v[7] = (short)f2bf(x1.w);
    *(bf16x8*)(Apk + (size_t)idx * 8) = v;
  } else {
    idx -= ACH;
    if (idx >= BCH) return;
    int c = idx % (cD / 8);                 // 0..159
    int n = (idx / (cD / 8)) % (2 * cL);    // 0..4095
    int b = idx / ((cD / 8) * 2 * cL);      // 0..3
    int j = n >> 1, o = n & 1;
    const float* src = h + ((size_t)b * cL + j) * cD + c * 8;
    const float* ws  = W + (size_t)o * (2 * cD) + c * 8;   // Wp row o
    float4 x0 = *(const float4*)src;
    float4 x1 = *(const float4*)(src + 4);
    float4 w0 = *(const float4*)ws;
    float4 w1 = *(const float4*)(ws + 4);
    bf16x8 v;
    v[0] = (short)f2bf(x0.x * w0.x); v[1] = (short)f2bf(x0.y * w0.y);
    v[2] = (short)f2bf(x0.z * w0.z); v[3] = (short)f2bf(x0.w * w0.w);
    v[4] = (short)f2bf(x1.x * w1.x); v[5] = (short)f2bf(x1.y * w1.y);
    v[6] = (short)f2bf(x1.z * w1.z); v[7] = (short)f2bf(x1.w * w1.w);
    *(bf16x8*)(Bpk + ((size_t)b * (2 * cL) + n) * cD + c * 8) = v;
  }
}

// ---------------- GEMM: 128x128 tile, BK=64, 4 waves (2x2), 16x16x32 bf16 ----------------
// LDS chunk swizzle: logical chunk kc of row r lives at physical chunk kc^(r&7)
// (involution; applied on the global SOURCE address for global_load_lds, and on ds_read).
template <int PACKED>
__global__ __launch_bounds__(256) void cph_gemm(
    const float* __restrict__ h, const float* __restrict__ W,
    const unsigned short* __restrict__ Apk, const unsigned short* __restrict__ Bpk,
    const float* __restrict__ bias, float* __restrict__ out) {
  __shared__ unsigned short Alds[BM][BK];
  __shared__ unsigned short Blds[BN][BK];

  // bijective XCD swizzle (NBLK % 8 == 0)
  int bid = ((int)blockIdx.x & 7) * (NBLK / 8) + ((int)blockIdx.x >> 3);
  int b   = bid / (MT * NT);
  int rem = bid % (MT * NT);
  int mt  = rem / NT, nt = rem % NT;

  int tid  = threadIdx.x;
  int wave = tid >> 6, lane = tid & 63;
  int wm = wave >> 1, wn = wave & 1;

  f32x4 acc[4][4] = {};

  for (int kt = 0; kt < KT; ++kt) {
    __syncthreads();  // previous tile's ds_reads done before overwrite
    if (PACKED) {
#pragma unroll
      for (int q = 0; q < 4; ++q) {
        int qi  = wave * 4 + q;          // 0..15 instruction slots
        int row = qi * 8 + (lane >> 3);  // lds row this lane's 16B lands in
        int pc  = lane & 7;              // lds physical chunk
        int gc  = pc ^ (row & 7);        // inverse-swizzled global chunk
        const unsigned short* gA =
            Apk + ((size_t)b * cL + mt * BM + row) * cD + kt * BK + gc * 8;
        GLOAD_LDS16(gA, (char*)(&Alds[0][0]) + qi * 1024);
        const unsigned short* gB =
            Bpk + ((size_t)b * NROW + nt * BN + row) * cD + kt * BK + gc * 8;
        GLOAD_LDS16(gB, (char*)(&Blds[0][0]) + qi * 1024);
      }
    } else {
      // fused fallback: fp32 -> bf16 reg-staging (used only if ws too small)
#pragma unroll
      for (int it = 0; it < 4; ++it) {
        int chunk = tid + it * 256;      // 0..1023
        int row = chunk >> 3, c = chunk & 7;
        int pc = c ^ (row & 7);
        const float* asrc = h + ((size_t)b * cL + mt * BM + row) * cD + kt * BK + c * 8;
        float4 a0 = *(const float4*)asrc;
        float4 a1 = *(const float4*)(asrc + 4);
        bf16x8 va;
        va[0] = (short)f2bf(a0.x); va[1] = (short)f2bf(a0.y);
        va[2] = (short)f2bf(a0.z); va[3] = (short)f2bf(a0.w);
        va[4] = (short)f2bf(a1.x); va[5] = (short)f2bf(a1.y);
        va[6] = (short)f2bf(a1.z); va[7] = (short)f2bf(a1.w);
        *(bf16x8*)&Alds[row][pc * 8] = va;

        int n = nt * BN + row;
        int j = n >> 1, o = n & 1;
        const float* bsrc = h + ((size_t)b * cL + j) * cD + kt * BK + c * 8;
        const float* wsrc = W + (size_t)o * (2 * cD) + kt * BK + c * 8;
        float4 b0 = *(const float4*)bsrc;
        float4 b1 = *(const float4*)(bsrc + 4);
        float4 w0 = *(const float4*)wsrc;
        float4 w1 = *(const float4*)(wsrc + 4);
        bf16x8 vb;
        vb[0] = (short)f2bf(b0.x * w0.x); vb[1] = (short)f2bf(b0.y * w0.y);
        vb[2] = (short)f2bf(b0.z * w0.z); vb[3] = (short)f2bf(b0.w * w0.w);
        vb[4] = (short)f2bf(b1.x * w1.x); vb[5] = (short)f2bf(b1.y * w1.y);
        vb[6] = (short)f2bf(b1.z * w1.z); vb[7] = (short)f2bf(b1.w * w1.w);
        *(bf16x8*)&Blds[row][pc * 8] = vb;
      }
    }
    __syncthreads();

#pragma unroll
    for (int kk = 0; kk < 2; ++kk) {
      int kc = kk * 4 + (lane >> 4);   // logical 8-elem chunk within BK
      bf16x8 af[4], bfr[4];
#pragma unroll
      for (int m = 0; m < 4; ++m) {
        int r = wm * 64 + m * 16 + (lane & 15);
        af[m] = *(const bf16x8*)&Alds[r][(kc ^ (r & 7)) * 8];
      }
#pragma unroll
      for (int n = 0; n < 4; ++n) {
        int r = wn * 64 + n * 16 + (lane & 15);
        bfr[n] = *(const bf16x8*)&Blds[r][(kc ^ (r & 7)) * 8];
      }
#pragma unroll
      for (int m = 0; m < 4; ++m)
#pragma unroll
        for (int n = 0; n < 4; ++n)
          acc[m][n] = __builtin_amdgcn_mfma_f32_16x16x32_bf16(af[m], bfr[n], acc[m][n], 0, 0, 0);
    }
  }

  // epilogue: C/D layout col = lane&15, row = (lane>>4)*4 + reg
  int i0 = mt * BM + wm * 64 + ((lane >> 4) << 2);
  int n0 = nt * BN + wn * 64 + (lane & 15);
  float badd = bias[n0 & 1];  // col parity is lane-invariant across nf (16*nf even)
  float* outb = out + (size_t)b * cL * NROW;
#pragma unroll
  for (int mf = 0; mf < 4; ++mf) {
#pragma unroll
    for (int r = 0; r < 4; ++r) {
      size_t rowoff = (size_t)(i0 + mf * 16 + r) * NROW;
#pragma unroll
      for (int nf = 0; nf < 4; ++nf)
        outb[rowoff + n0 + nf * 16] = acc[mf][nf][r] + badd;
    }
  }
}

extern "C" void kernel_launch(void* const* d_in, const int* in_sizes, int n_in,
                              void* d_out, int out_size, void* d_ws, size_t ws_size,
                              hipStream_t stream) {
  const float* h    = (const float*)d_in[0];
  const float* W    = (const float*)d_in[1];
  const float* bias = (const float*)d_in[2];
  float* out        = (float*)d_out;

  size_t a_elems = (size_t)cB * cL * cD;          // 10.49M
  size_t b_elems = (size_t)cB * 2 * cL * cD;      // 20.97M
  size_t need = (a_elems + b_elems) * sizeof(unsigned short);  // ~63 MB

  if (ws_size >= need) {
    unsigned short* Apk = (unsigned short*)d_ws;
    unsigned short* Bpk = Apk + a_elems;
    int total_chunks = ACH + BCH;
    cph_pack<<<(total_chunks + 255) / 256, 256, 0, stream>>>(h, W, Apk, Bpk);
    cph_gemm<1><<<NBLK, 256, 0, stream>>>(h, W, Apk, Bpk, bias, out);
  } else {
    cph_gemm<0><<<NBLK, 256, 0, stream>>>(h, W, nullptr, nullptr, bias, out);
  }
}

// Round 3
// 124.935 us; speedup vs baseline: 1.1252x; 1.1252x over previous
//
#include <hip/hip_runtime.h>
#include <hip/hip_bf16.h>

// ContactPredictionHead: logits[b,i,j,o] = sum_d h[b,i,d]*h[b,j,d]*Wp[o,d] + bias[o]
// (diff term is antisymmetric -> cancels under symmetrization; prod term is symmetric.)
// Batched GEMM: per batch  C[2048 x 4096] = A[2048 x 1280] * Beff^T,
//   Beff[2j+o, d] = h[b,j,d] * Wp[o,d],  row-major C == d_out layout.
// Round 3: C_o[i,j] symmetric -> GEMM computes only lower-triangle 128x128
// (i,j)-supertiles (136/256 per batch, 53% of FLOPs) with the proven round-1
// epilogue; a SEPARATE tiled-transpose kernel mirrors the 120 strict-lower
// supertiles to the upper triangle (race-free by construction: kernel-boundary
// ordering, single barrier, disjoint write regions).

typedef __attribute__((ext_vector_type(8))) short bf16x8;
typedef __attribute__((ext_vector_type(4))) float f32x4;

constexpr int cB = 4, cL = 2048, cD = 1280, cO = 2;
constexpr int BM = 128, BN = 128, BK = 64;
constexpr int KT = cD / BK;            // 20
constexpr int NROW = cL * cO;          // 4096
constexpr int NSUP = 136;              // 16*17/2 lower-tri supertiles per batch
constexpr int NBLK = cB * NSUP * 2;    // 1088 (two 128-col tiles per supertile); %8==0
constexpr int NMIR = cB * 120 * 4;     // 1920 mirror blocks (120 strict-lower pairs x 4 quads)

__device__ __forceinline__ unsigned short f2bf(float f) {
  unsigned int u = __float_as_uint(f);
  u += 0x7fffu + ((u >> 16) & 1u);
  return (unsigned short)(u >> 16);
}

#define GLOAD_LDS16(g, l)                                           \
  __builtin_amdgcn_global_load_lds(                                 \
      (const __attribute__((address_space(1))) void*)(g),           \
      (__attribute__((address_space(3))) void*)(l), 16, 0, 0)

// ---------------- pack: h -> bf16 A, (h*Wp) -> bf16 Beff ----------------
constexpr int ACH = cB * cL * cD / 8;       // 1,310,720 chunks of 8
constexpr int BCH = cB * 2 * cL * cD / 8;   // 2,621,440 chunks of 8

__global__ __launch_bounds__(256) void cph_pack(
    const float* __restrict__ h, const float* __restrict__ W,
    unsigned short* __restrict__ Apk, unsigned short* __restrict__ Bpk) {
  int idx = blockIdx.x * 256 + threadIdx.x;
  if (idx < ACH) {
    const float* src = h + (size_t)idx * 8;
    float4 x0 = *(const float4*)src;
    float4 x1 = *(const float4*)(src + 4);
    bf16x8 v;
    v[0] = (short)f2bf(x0.x); v[1] = (short)f2bf(x0.y);
    v[2] = (short)f2bf(x0.z); v[3] = (short)f2bf(x0.w);
    v[4] = (short)f2bf(x1.x); v[5] = (short)f2bf(x1.y);
    v[6] = (short)f2bf(x1.z); v[7] = (short)f2bf(x1.w);
    *(bf16x8*)(Apk + (size_t)idx * 8) = v;
  } else {
    idx -= ACH;
    if (idx >= BCH) return;
    int c = idx % (cD / 8);                 // 0..159
    int n = (idx / (cD / 8)) % (2 * cL);    // 0..4095
    int b = idx / ((cD / 8) * 2 * cL);      // 0..3
    int j = n >> 1, o = n & 1;
    const float* src = h + ((size_t)b * cL + j) * cD + c * 8;
    const float* ws  = W + (size_t)o * (2 * cD) + c * 8;   // Wp row o
    float4 x0 = *(const float4*)src;
    float4 x1 = *(const float4*)(src + 4);
    float4 w0 = *(const float4*)ws;
    float4 w1 = *(const float4*)(ws + 4);
    bf16x8 v;
    v[0] = (short)f2bf(x0.x * w0.x); v[1] = (short)f2bf(x0.y * w0.y);
    v[2] = (short)f2bf(x0.z * w0.z); v[3] = (short)f2bf(x0.w * w0.w);
    v[4] = (short)f2bf(x1.x * w1.x); v[5] = (short)f2bf(x1.y * w1.y);
    v[6] = (short)f2bf(x1.z * w1.z); v[7] = (short)f2bf(x1.w * w1.w);
    *(bf16x8*)(Bpk + ((size_t)b * (2 * cL) + n) * cD + c * 8) = v;
  }
}

// ---------------- GEMM: 128x128 tile, BK=64, 4 waves (2x2), 16x16x32 bf16 ----------------
// LDS chunk swizzle: logical chunk kc of row r lives at physical chunk kc^(r&7)
// (applied on the global SOURCE address for global_load_lds, and on ds_read).
template <int PACKED>
__global__ __launch_bounds__(256) void cph_gemm(
    const float* __restrict__ h, const float* __restrict__ W,
    const unsigned short* __restrict__ Apk, const unsigned short* __restrict__ Bpk,
    const float* __restrict__ bias, float* __restrict__ out) {
  __shared__ unsigned short Alds[BM][BK];
  __shared__ unsigned short Blds[BN][BK];

  // bijective XCD swizzle (NBLK % 8 == 0)
  int bid = ((int)blockIdx.x & 7) * (NBLK / 8) + ((int)blockIdx.x >> 3);
  int b   = bid / (NSUP * 2);
  int rem = bid % (NSUP * 2);
  int s   = rem >> 1, hh = rem & 1;
  // triangular decode: s -> (a,bb) with a >= bb
  int a = 0;
  while ((a + 1) * (a + 2) / 2 <= s) ++a;
  int bb = s - a * (a + 1) / 2;
  int mt = a;                 // i-tile (128 rows)
  int nt = 2 * bb + hh;       // n-tile (128 cols = 64 j x 2 o)

  int tid  = threadIdx.x;
  int wave = tid >> 6, lane = tid & 63;
  int wm = wave >> 1, wn = wave & 1;

  f32x4 acc[4][4] = {};

  for (int kt = 0; kt < KT; ++kt) {
    __syncthreads();  // previous tile's ds_reads done before overwrite
    if (PACKED) {
#pragma unroll
      for (int q = 0; q < 4; ++q) {
        int qi  = wave * 4 + q;          // 0..15 instruction slots
        int row = qi * 8 + (lane >> 3);  // lds row this lane's 16B lands in
        int pc  = lane & 7;              // lds physical chunk
        int gc  = pc ^ (row & 7);        // inverse-swizzled global chunk
        const unsigned short* gA =
            Apk + ((size_t)b * cL + mt * BM + row) * cD + kt * BK + gc * 8;
        GLOAD_LDS16(gA, (char*)(&Alds[0][0]) + qi * 1024);
        const unsigned short* gB =
            Bpk + ((size_t)b * NROW + nt * BN + row) * cD + kt * BK + gc * 8;
        GLOAD_LDS16(gB, (char*)(&Blds[0][0]) + qi * 1024);
      }
    } else {
      // fused fallback: fp32 -> bf16 reg-staging (used only if ws too small)
#pragma unroll
      for (int it = 0; it < 4; ++it) {
        int chunk = tid + it * 256;      // 0..1023
        int row = chunk >> 3, c = chunk & 7;
        int pc = c ^ (row & 7);
        const float* asrc = h + ((size_t)b * cL + mt * BM + row) * cD + kt * BK + c * 8;
        float4 a0 = *(const float4*)asrc;
        float4 a1 = *(const float4*)(asrc + 4);
        bf16x8 va;
        va[0] = (short)f2bf(a0.x); va[1] = (short)f2bf(a0.y);
        va[2] = (short)f2bf(a0.z); va[3] = (short)f2bf(a0.w);
        va[4] = (short)f2bf(a1.x); va[5] = (short)f2bf(a1.y);
        va[6] = (short)f2bf(a1.z); va[7] = (short)f2bf(a1.w);
        *(bf16x8*)&Alds[row][pc * 8] = va;

        int n = nt * BN + row;
        int j = n >> 1, o = n & 1;
        const float* bsrc = h + ((size_t)b * cL + j) * cD + kt * BK + c * 8;
        const float* wsrc = W + (size_t)o * (2 * cD) + kt * BK + c * 8;
        float4 b0 = *(const float4*)bsrc;
        float4 b1 = *(const float4*)(bsrc + 4);
        float4 w0 = *(const float4*)wsrc;
        float4 w1 = *(const float4*)(wsrc + 4);
        bf16x8 vb;
        vb[0] = (short)f2bf(b0.x * w0.x); vb[1] = (short)f2bf(b0.y * w0.y);
        vb[2] = (short)f2bf(b0.z * w0.z); vb[3] = (short)f2bf(b0.w * w0.w);
        vb[4] = (short)f2bf(b1.x * w1.x); vb[5] = (short)f2bf(b1.y * w1.y);
        vb[6] = (short)f2bf(b1.z * w1.z); vb[7] = (short)f2bf(b1.w * w1.w);
        *(bf16x8*)&Blds[row][pc * 8] = vb;
      }
    }
    __syncthreads();

#pragma unroll
    for (int kk = 0; kk < 2; ++kk) {
      int kc = kk * 4 + (lane >> 4);   // logical 8-elem chunk within BK
      bf16x8 af[4], bfr[4];
#pragma unroll
      for (int m = 0; m < 4; ++m) {
        int r = wm * 64 + m * 16 + (lane & 15);
        af[m] = *(const bf16x8*)&Alds[r][(kc ^ (r & 7)) * 8];
      }
#pragma unroll
      for (int n = 0; n < 4; ++n) {
        int r = wn * 64 + n * 16 + (lane & 15);
        bfr[n] = *(const bf16x8*)&Blds[r][(kc ^ (r & 7)) * 8];
      }
#pragma unroll
      for (int m = 0; m < 4; ++m)
#pragma unroll
        for (int n = 0; n < 4; ++n)
          acc[m][n] = __builtin_amdgcn_mfma_f32_16x16x32_bf16(af[m], bfr[n], acc[m][n], 0, 0, 0);
    }
  }

  // epilogue: C/D layout col = lane&15, row = (lane>>4)*4 + reg
  int i0 = mt * BM + wm * 64 + ((lane >> 4) << 2);
  int n0 = nt * BN + wn * 64 + (lane & 15);
  float badd = bias[n0 & 1];  // col parity is lane-invariant across nf (16*nf even)
  float* outb = out + (size_t)b * cL * NROW;
#pragma unroll
  for (int mf = 0; mf < 4; ++mf) {
#pragma unroll
    for (int r = 0; r < 4; ++r) {
      size_t rowoff = (size_t)(i0 + mf * 16 + r) * NROW;
#pragma unroll
      for (int nf = 0; nf < 4; ++nf)
        outb[rowoff + n0 + nf * 16] = acc[mf][nf][r] + badd;
    }
  }
}

// ---------------- mirror: out[b, j, 2i+o] = out[b, i, 2j+o] for strict-upper ----
// 64x64 (i,j)-quad per block; coalesced float4 read + float4 write through LDS.
__global__ __launch_bounds__(256) void cph_mirror(float* __restrict__ out) {
  __shared__ float S[64][132];   // 33792 B; stride 132 keeps float4-aligned rows
  int idx = (int)blockIdx.x;
  int b   = idx / 480;
  int rem = idx % 480;
  int sup = rem >> 2, quad = rem & 3;
  // strict-lower decode: sup -> (a,bb), a > bb ; sup = a*(a-1)/2 + bb
  int a = 1;
  while (a * (a + 1) / 2 <= sup) ++a;
  int bb = sup - a * (a - 1) / 2;
  int i0 = a * 128 + (quad >> 1) * 64;
  int j0 = bb * 128 + (quad & 1) * 64;
  float* outb = out + (size_t)b * cL * NROW;
  int tid = threadIdx.x;

  // load: S[il][c] = out[b, i0+il, 2*j0 + c], c in [0,128)
#pragma unroll
  for (int it = 0; it < 8; ++it) {
    int t = it * 256 + tid;
    int il = t >> 5, c4 = (t & 31) << 2;
    float4 v = *(const float4*)&outb[(size_t)(i0 + il) * NROW + 2 * j0 + c4];
    *(float4*)&S[il][c4] = v;
  }
  __syncthreads();
  // store: out[b, j0+jl, 2*(i0+il)+o] = S[il][2*jl+o]
#pragma unroll
  for (int it = 0; it < 8; ++it) {
    int t = it * 256 + tid;
    int jl = t >> 5, c4 = (t & 31) << 2;
    int il = c4 >> 1;
    float4 v;
    v.x = S[il][2 * jl];
    v.y = S[il][2 * jl + 1];
    v.z = S[il + 1][2 * jl];
    v.w = S[il + 1][2 * jl + 1];
    *(float4*)&outb[(size_t)(j0 + jl) * NROW + 2 * (size_t)i0 + c4] = v;
  }
}

extern "C" void kernel_launch(void* const* d_in, const int* in_sizes, int n_in,
                              void* d_out, int out_size, void* d_ws, size_t ws_size,
                              hipStream_t stream) {
  const float* h    = (const float*)d_in[0];
  const float* W    = (const float*)d_in[1];
  const float* bias = (const float*)d_in[2];
  float* out        = (float*)d_out;

  size_t a_elems = (size_t)cB * cL * cD;          // 10.49M
  size_t b_elems = (size_t)cB * 2 * cL * cD;      // 20.97M
  size_t need = (a_elems + b_elems) * sizeof(unsigned short);  // ~63 MB

  if (ws_size >= need) {
    unsigned short* Apk = (unsigned short*)d_ws;
    unsigned short* Bpk = Apk + a_elems;
    int total_chunks = ACH + BCH;
    cph_pack<<<(total_chunks + 255) / 256, 256, 0, stream>>>(h, W, Apk, Bpk);
    cph_gemm<1><<<NBLK, 256, 0, stream>>>(h, W, Apk, Bpk, bias, out);
  } else {
    cph_gemm<0><<<NBLK, 256, 0, stream>>>(h, W, nullptr, nullptr, bias, out);
  }
  cph_mirror<<<NMIR, 256, 0, stream>>>(out);
}